// Round 19
// baseline (145.908 us; speedup 1.0000x reference)
//
#include <hip/hip_runtime.h>
#include <hip/hip_fp16.h>

// GCN 2-layer forward, round 19:
//   R18 + k_fused at 8 nodes/wave (was 16): grid doubles -> full 32-wave/CU
//   residency, serial gather chain per wave halves. MLP runs a half-filled
//   16-row MFMA tile (rows 8-15 garbage, discarded; A-reads masked lo&7,
//   stores guarded hi<2). Everything else identical to R18.
//   ax[v]  = dinv[v]*(sum xs[s] + xs[v]),  xs = fp16(dinv.*x)
//   h2s    = fp16(dinv .* (relu(ax@W1+b1) @ W2))   [MFMA]
//   out[v] = dinv[v]*(sum h2s[s] + h2s[v]) + b2

#define F_IN 64
#define HDIM 128
#define CDIM 32
#define BK 256          // nodes per bucket (== kb_finalize blockDim)
#define BCAP 6144       // edge capacity per bucket (mean 4090 @ n=100K,E=1.6M)
#define SC_CHUNK 4096   // edges per kb_scatter workgroup
#define NPW 8           // nodes per wave in k_fused

struct h4 { __half2 a, b; };  // 8-byte packed 4x fp16

typedef _Float16 half8 __attribute__((ext_vector_type(8)));
typedef float f32x4 __attribute__((ext_vector_type(4)));

__device__ __forceinline__ __half2 hshfl_xor(__half2 h, int d) {
    union { __half2 h2; int i; } u;
    u.h2 = h;
    u.i = __shfl_xor(u.i, d);
    return u.h2;
}

// ---------- scatter: LDS hist -> cursor reservation -> packed staging ----------
// extra block (blockIdx == nchunks): weight conversion + zero-row padding
__global__ void kb_scatter(const int* __restrict__ src, const int* __restrict__ dst,
                           int e, int nbk, int nchunks, int* __restrict__ bucketCursor,
                           unsigned* __restrict__ staging,
                           const float* __restrict__ W1, const float* __restrict__ W2,
                           _Float16* __restrict__ W1T, _Float16* __restrict__ W2T,
                           h4* __restrict__ xs, h4* __restrict__ h2s4, int n) {
    int tid = threadIdx.x;
    if (blockIdx.x == nchunks) {  // aux block
        for (int i = tid; i < F_IN * HDIM + HDIM * CDIM; i += blockDim.x) {
            if (i < F_IN * HDIM) {
                int k = i >> 7, c = i & 127;
                W1T[c * F_IN + k] = (_Float16)W1[i];
            } else {
                int j = i - F_IN * HDIM;
                int k = j >> 5, c = j & 31;
                W2T[c * HDIM + k] = (_Float16)W2[j];
            }
        }
        h4 z; z.a = __float2half2_rn(0.f); z.b = z.a;
        if (tid < 16) xs[(size_t)n * 16 + tid] = z;               // zero row xs[n]
        else if (tid < 24) h2s4[(size_t)n * 8 + (tid - 16)] = z;  // zero row h2s[n]
        return;
    }
    __shared__ int lh[512];
    __shared__ int lbase[512];
    __shared__ int dstS[SC_CHUNK];
    int c0 = blockIdx.x * SC_CHUNK;
    int m = min(SC_CHUNK, e - c0);
    for (int i = tid; i < nbk; i += blockDim.x) lh[i] = 0;
    __syncthreads();
    for (int i = tid; i < m; i += blockDim.x) {
        int d = dst[c0 + i];
        dstS[i] = d;
        atomicAdd(&lh[d >> 8], 1);
    }
    __syncthreads();
    for (int i = tid; i < nbk; i += blockDim.x) {
        int c = lh[i];
        lbase[i] = c ? atomicAdd(&bucketCursor[i], c) : 0;
        lh[i] = 0;  // becomes local cursor
    }
    __syncthreads();
    for (int i = tid; i < m; i += blockDim.x) {
        int d = dstS[i];
        int b = d >> 8;
        int r = atomicAdd(&lh[b], 1);
        staging[(size_t)b * BCAP + lbase[b] + r] =
            ((unsigned)(d & (BK - 1)) << 24) | (unsigned)src[c0 + i];
    }
}

// fused single-pass: staging copied to LDS during degree count, in-bucket scan
// -> rc(int2 rowptr,deg)/dinv, counting sort from LDS, bucket-local prescale
__global__ __launch_bounds__(256) void kb_finalize(
    const unsigned* __restrict__ staging, const int* __restrict__ bucketCursor,
    int2* __restrict__ rc, float* __restrict__ dinv,
    int* __restrict__ col, const float* __restrict__ x, h4* __restrict__ xs, int n) {
    __shared__ unsigned eS[BCAP];   // 24KB bucket edge cache
    __shared__ int lc[BK];
    __shared__ int lscan[BK];
    __shared__ float dinvS[BK];
    int b = blockIdx.x;
    int tid = threadIdx.x;
    lc[tid] = 0;
    __syncthreads();
    int beg = b * BCAP;
    int ne = bucketCursor[b];
    for (int i = tid; i < ne; i += blockDim.x) {
        unsigned sd = staging[beg + i];
        eS[i] = sd;
        atomicAdd(&lc[sd >> 24], 1);
    }
    __syncthreads();
    int deg = lc[tid];
    lscan[tid] = deg;
    __syncthreads();
    for (int off = 1; off < BK; off <<= 1) {
        int t = (tid >= off) ? lscan[tid - off] : 0;
        __syncthreads();
        lscan[tid] += t;
        __syncthreads();
    }
    int rp = beg + lscan[tid] - deg;   // bucket-padded CSR offset
    int v = b * BK + tid;
    float dv = rsqrtf((float)(deg + 1));
    if (v < n) {
        rc[v] = make_int2(rp, deg);
        dinv[v] = dv;
    }
    dinvS[tid] = dv;
    lc[tid] = rp;  // becomes cursor
    __syncthreads();
    for (int i = tid; i < ne; i += blockDim.x) {
        unsigned sd = eS[i];
        int pos = atomicAdd(&lc[sd >> 24], 1);
        col[pos] = (int)(sd & 0xFFFFFFu);
    }
    // bucket-local prescale: xs[v] = fp16(dinv[v] * x[v])  (coalesced)
    int v0 = b * BK;
    int rows = min(BK, n - v0);
    for (int t = tid; t < rows * 16; t += blockDim.x) {
        int row = t >> 4, q = t & 15;
        float s = dinvS[row];
        float4 val = ((const float4*)x)[(size_t)(v0 + row) * 16 + q];
        h4 o;
        o.a = __floats2half2_rn(val.x * s, val.y * s);
        o.b = __floats2half2_rn(val.z * s, val.w * s);
        xs[(size_t)(v0 + row) * 16 + q] = o;
    }
}

// ---------- fused gather1 + MFMA MLP (8 nodes/wave) ----------
// block = 256 = 4 waves; wave owns 8 nodes: gathers in 2 QUAD steps
// (4 nodes x 2-deep = 8 row-loads in flight/lane) into a wave-private LDS
// arena; axs (stride 72, rows 0..7) consumed to registers before hbuf
// (stride 136, rows 0..7) overwrites the arena. MFMA tile half-filled:
// A-row reads masked (lo&7), stores guarded (hi<2). No __syncthreads.
__global__ __launch_bounds__(256) void k_fused(
    const _Float16* __restrict__ xs, const int2* __restrict__ rc,
    const int* __restrict__ col,
    const float* __restrict__ dinv, const _Float16* __restrict__ W1T,
    const float* __restrict__ b1, const _Float16* __restrict__ W2T,
    __half* __restrict__ h2s, int n) {
    __shared__ _Float16 smem[4][NPW * 136 + 8];  // per-wave arena
    int tid = threadIdx.x;
    int w = tid >> 6, lane = tid & 63;
    int m0 = blockIdx.x * (4 * NPW) + w * NPW;
    if (m0 >= n) return;  // wave-uniform; no barriers in this kernel
    int g = lane >> 3, l = lane & 7;
    int lo = lane & 15, hi = lane >> 4;
    _Float16* sm = smem[w];

    // ---- gather phase: 2 quads ----
    for (int p = 0; p < 2; ++p) {
        int v0 = m0 + 4 * p;
        int2 rc0 = make_int2(0, 0), rc1 = rc0, rc2 = rc0, rc3 = rc0;
        if (v0 < n)     rc0 = rc[v0];
        if (v0 + 1 < n) rc1 = rc[v0 + 1];
        if (v0 + 2 < n) rc2 = rc[v0 + 2];
        if (v0 + 3 < n) rc3 = rc[v0 + 3];
        int beg0 = rc0.x, deg0 = rc0.y;
        int beg1 = rc1.x, deg1 = rc1.y;
        int beg2 = rc2.x, deg2 = rc2.y;
        int beg3 = rc3.x, deg3 = rc3.y;
        int dmax = max(max(deg0, deg1), max(deg2, deg3));

        __half2 z = __float2half2_rn(0.f);
        __half2 a00 = z, a01 = z, a02 = z, a03 = z;
        __half2 a10 = z, a11 = z, a12 = z, a13 = z;
        __half2 a20 = z, a21 = z, a22 = z, a23 = z;
        __half2 a30 = z, a31 = z, a32 = z, a33 = z;

        for (int j = g; j < dmax; j += 16) {
            int jb = j + 8;
            int s00 = (j  < deg0) ? col[beg0 + j]  : n;
            int s01 = (jb < deg0) ? col[beg0 + jb] : n;
            int s10 = (j  < deg1) ? col[beg1 + j]  : n;
            int s11 = (jb < deg1) ? col[beg1 + jb] : n;
            int s20 = (j  < deg2) ? col[beg2 + j]  : n;
            int s21 = (jb < deg2) ? col[beg2 + jb] : n;
            int s30 = (j  < deg3) ? col[beg3 + j]  : n;
            int s31 = (jb < deg3) ? col[beg3 + jb] : n;
            float4 r00 = ((const float4*)(xs + (size_t)s00 * F_IN))[l];
            float4 r01 = ((const float4*)(xs + (size_t)s01 * F_IN))[l];
            float4 r10 = ((const float4*)(xs + (size_t)s10 * F_IN))[l];
            float4 r11 = ((const float4*)(xs + (size_t)s11 * F_IN))[l];
            float4 r20 = ((const float4*)(xs + (size_t)s20 * F_IN))[l];
            float4 r21 = ((const float4*)(xs + (size_t)s21 * F_IN))[l];
            float4 r30 = ((const float4*)(xs + (size_t)s30 * F_IN))[l];
            float4 r31 = ((const float4*)(xs + (size_t)s31 * F_IN))[l];
            a00 = __hadd2(a00, *(__half2*)&r00.x); a01 = __hadd2(a01, *(__half2*)&r00.y);
            a02 = __hadd2(a02, *(__half2*)&r00.z); a03 = __hadd2(a03, *(__half2*)&r00.w);
            a00 = __hadd2(a00, *(__half2*)&r01.x); a01 = __hadd2(a01, *(__half2*)&r01.y);
            a02 = __hadd2(a02, *(__half2*)&r01.z); a03 = __hadd2(a03, *(__half2*)&r01.w);
            a10 = __hadd2(a10, *(__half2*)&r10.x); a11 = __hadd2(a11, *(__half2*)&r10.y);
            a12 = __hadd2(a12, *(__half2*)&r10.z); a13 = __hadd2(a13, *(__half2*)&r10.w);
            a10 = __hadd2(a10, *(__half2*)&r11.x); a11 = __hadd2(a11, *(__half2*)&r11.y);
            a12 = __hadd2(a12, *(__half2*)&r11.z); a13 = __hadd2(a13, *(__half2*)&r11.w);
            a20 = __hadd2(a20, *(__half2*)&r20.x); a21 = __hadd2(a21, *(__half2*)&r20.y);
            a22 = __hadd2(a22, *(__half2*)&r20.z); a23 = __hadd2(a23, *(__half2*)&r20.w);
            a20 = __hadd2(a20, *(__half2*)&r21.x); a21 = __hadd2(a21, *(__half2*)&r21.y);
            a22 = __hadd2(a22, *(__half2*)&r21.z); a23 = __hadd2(a23, *(__half2*)&r21.w);
            a30 = __hadd2(a30, *(__half2*)&r30.x); a31 = __hadd2(a31, *(__half2*)&r30.y);
            a32 = __hadd2(a32, *(__half2*)&r30.z); a33 = __hadd2(a33, *(__half2*)&r30.w);
            a30 = __hadd2(a30, *(__half2*)&r31.x); a31 = __hadd2(a31, *(__half2*)&r31.y);
            a32 = __hadd2(a32, *(__half2*)&r31.z); a33 = __hadd2(a33, *(__half2*)&r31.w);
        }

        // packed butterfly across the 8 groups (xor 8, 16, 32)
#pragma unroll
        for (int d = 8; d <= 32; d <<= 1) {
            a00 = __hadd2(a00, hshfl_xor(a00, d)); a01 = __hadd2(a01, hshfl_xor(a01, d));
            a02 = __hadd2(a02, hshfl_xor(a02, d)); a03 = __hadd2(a03, hshfl_xor(a03, d));
            a10 = __hadd2(a10, hshfl_xor(a10, d)); a11 = __hadd2(a11, hshfl_xor(a11, d));
            a12 = __hadd2(a12, hshfl_xor(a12, d)); a13 = __hadd2(a13, hshfl_xor(a13, d));
            a20 = __hadd2(a20, hshfl_xor(a20, d)); a21 = __hadd2(a21, hshfl_xor(a21, d));
            a22 = __hadd2(a22, hshfl_xor(a22, d)); a23 = __hadd2(a23, hshfl_xor(a23, d));
            a30 = __hadd2(a30, hshfl_xor(a30, d)); a31 = __hadd2(a31, hshfl_xor(a31, d));
            a32 = __hadd2(a32, hshfl_xor(a32, d)); a33 = __hadd2(a33, hshfl_xor(a33, d));
        }

        // selection (register moves only) + shared epilogue
        if (g < 4) {
            int v = v0 + g;
            if (v < n) {
                __half2 A0, A1, A2, A3;
                if (g == 0)      { A0 = a00; A1 = a01; A2 = a02; A3 = a03; }
                else if (g == 1) { A0 = a10; A1 = a11; A2 = a12; A3 = a13; }
                else if (g == 2) { A0 = a20; A1 = a21; A2 = a22; A3 = a23; }
                else             { A0 = a30; A1 = a31; A2 = a32; A3 = a33; }
                float dv = dinv[v];
                float4 sr = ((const float4*)(xs + (size_t)v * F_IN))[l];
                float2 f0 = __half22float2(A0), f1 = __half22float2(A1);
                float2 f2 = __half22float2(A2), f3 = __half22float2(A3);
                float2 s0 = __half22float2(*(__half2*)&sr.x);
                float2 s1 = __half22float2(*(__half2*)&sr.y);
                float2 s2 = __half22float2(*(__half2*)&sr.z);
                float2 s3 = __half22float2(*(__half2*)&sr.w);
                __half2 o0 = __floats2half2_rn(dv * (f0.x + s0.x), dv * (f0.y + s0.y));
                __half2 o1 = __floats2half2_rn(dv * (f1.x + s1.x), dv * (f1.y + s1.y));
                __half2 o2 = __floats2half2_rn(dv * (f2.x + s2.x), dv * (f2.y + s2.y));
                __half2 o3 = __floats2half2_rn(dv * (f3.x + s3.x), dv * (f3.y + s3.y));
                float4 o;
                o.x = *(float*)&o0; o.y = *(float*)&o1; o.z = *(float*)&o2; o.w = *(float*)&o3;
                *(float4*)&sm[(4 * p + g) * 72 + l * 8] = o;   // axs row 0..7
            }
        }
    }

    // ---- layer 1 MFMA: A from axs rows 0..7 (masked lo&7; rows 8-15 dup) ----
    int lom = lo & 7;
    half8 a0 = *(half8*)&sm[lom * 72 + hi * 8];
    half8 a1 = *(half8*)&sm[lom * 72 + 32 + hi * 8];

    float b1v[8];
    f32x4 acc[8];
#pragma unroll
    for (int j = 0; j < 8; ++j) {
        b1v[j] = b1[j * 16 + lo];
        const half8* bptr = (const half8*)(W1T + (size_t)(j * 16 + lo) * F_IN);
        half8 bf0 = bptr[hi];
        half8 bf1 = bptr[4 + hi];
        f32x4 c = {0.f, 0.f, 0.f, 0.f};
        c = __builtin_amdgcn_mfma_f32_16x16x32_f16(a0, bf0, c, 0, 0, 0);
        c = __builtin_amdgcn_mfma_f32_16x16x32_f16(a1, bf1, c, 0, 0, 0);
        acc[j] = c;
    }

    // epilogue 1: bias + relu -> hbuf rows 0..7 (only hi<2 rows valid)
    if (hi < 2) {
#pragma unroll
        for (int j = 0; j < 8; ++j) {
#pragma unroll
            for (int r = 0; r < 4; ++r) {
                float hv = acc[j][r] + b1v[j];
                sm[(hi * 4 + r) * 136 + j * 16 + lo] = (_Float16)(hv > 0.f ? hv : 0.f);
            }
        }
    }

    // ---- layer 2 MFMA: A from hbuf rows 0..7 (masked) ----
    f32x4 acc2[2] = {{0.f, 0.f, 0.f, 0.f}, {0.f, 0.f, 0.f, 0.f}};
#pragma unroll
    for (int ks = 0; ks < 4; ++ks) {
        half8 a = *(half8*)&sm[lom * 136 + ks * 32 + hi * 8];
#pragma unroll
        for (int t = 0; t < 2; ++t) {
            const half8* b2p = (const half8*)(W2T + (size_t)(t * 16 + lo) * HDIM);
            acc2[t] = __builtin_amdgcn_mfma_f32_16x16x32_f16(a, b2p[ks * 4 + hi], acc2[t], 0, 0, 0);
        }
    }

    if (hi < 2) {
#pragma unroll
        for (int r = 0; r < 4; ++r) {
            int R = m0 + hi * 4 + r;
            if (R < n) {
                float dv = dinv[R];
                h2s[(size_t)R * CDIM + lo]      = __float2half(dv * acc2[0][r]);
                h2s[(size_t)R * CDIM + 16 + lo] = __float2half(dv * acc2[1][r]);
            }
        }
    }
}

// ---------- gather 2: wave = 4 nodes (16-lane slots), 4-lane groups, 4-deep ----
__global__ void k_gather2(const _Float16* __restrict__ h2s, const int2* __restrict__ rc,
                          const int* __restrict__ col,
                          const float* __restrict__ dinv, const float* __restrict__ b2,
                          float* __restrict__ out, int n) {
    int tid = threadIdx.x;
    int w = tid >> 6, lane = tid & 63;
    int v0w = blockIdx.x * 16 + w * 4;   // first node of this wave
    if (v0w >= n) return;                // wave-uniform
    int slot = lane >> 4;
    int v = v0w + slot;
    bool valid = v < n;
    int g = (lane >> 2) & 3, l = lane & 3;
    int2 rcv = valid ? rc[v] : make_int2(0, 0);
    int beg = rcv.x, deg = rcv.y;

    __half2 zz = __float2half2_rn(0.f);
    __half2 a0 = zz, a1 = zz, a2 = zz, a3 = zz;
    __half2 c0 = zz, c1 = zz, c2 = zz, c3 = zz;
    __half2 d0 = zz, d1 = zz, d2 = zz, d3 = zz;
    __half2 e0 = zz, e1 = zz, e2 = zz, e3 = zz;
    for (int j = g; j < deg; j += 16) {
        int s0 = col[beg + j];
        int s1 = (j + 4  < deg) ? col[beg + j + 4]  : n;
        int s2 = (j + 8  < deg) ? col[beg + j + 8]  : n;
        int s3 = (j + 12 < deg) ? col[beg + j + 12] : n;
        float4 r0 = ((const float4*)(h2s + (size_t)s0 * CDIM))[l];
        float4 r1 = ((const float4*)(h2s + (size_t)s1 * CDIM))[l];
        float4 r2 = ((const float4*)(h2s + (size_t)s2 * CDIM))[l];
        float4 r3 = ((const float4*)(h2s + (size_t)s3 * CDIM))[l];
        a0 = __hadd2(a0, *(__half2*)&r0.x); a1 = __hadd2(a1, *(__half2*)&r0.y);
        a2 = __hadd2(a2, *(__half2*)&r0.z); a3 = __hadd2(a3, *(__half2*)&r0.w);
        c0 = __hadd2(c0, *(__half2*)&r1.x); c1 = __hadd2(c1, *(__half2*)&r1.y);
        c2 = __hadd2(c2, *(__half2*)&r1.z); c3 = __hadd2(c3, *(__half2*)&r1.w);
        d0 = __hadd2(d0, *(__half2*)&r2.x); d1 = __hadd2(d1, *(__half2*)&r2.y);
        d2 = __hadd2(d2, *(__half2*)&r2.z); d3 = __hadd2(d3, *(__half2*)&r2.w);
        e0 = __hadd2(e0, *(__half2*)&r3.x); e1 = __hadd2(e1, *(__half2*)&r3.y);
        e2 = __hadd2(e2, *(__half2*)&r3.z); e3 = __hadd2(e3, *(__half2*)&r3.w);
    }
    a0 = __hadd2(__hadd2(a0, c0), __hadd2(d0, e0));
    a1 = __hadd2(__hadd2(a1, c1), __hadd2(d1, e1));
    a2 = __hadd2(__hadd2(a2, c2), __hadd2(d2, e2));
    a3 = __hadd2(__hadd2(a3, c3), __hadd2(d3, e3));

    // packed butterfly across the 4 groups within the slot (xor 4, 8)
#pragma unroll
    for (int d = 4; d <= 8; d <<= 1) {
        a0 = __hadd2(a0, hshfl_xor(a0, d)); a1 = __hadd2(a1, hshfl_xor(a1, d));
        a2 = __hadd2(a2, hshfl_xor(a2, d)); a3 = __hadd2(a3, hshfl_xor(a3, d));
    }

    if (g == 0 && valid) {
        float dv = dinv[v];
        float4 sr = ((const float4*)(h2s + (size_t)v * CDIM))[l];
        float2 f0 = __half22float2(a0), f1 = __half22float2(a1);
        float2 f2 = __half22float2(a2), f3 = __half22float2(a3);
        float2 s0 = __half22float2(*(__half2*)&sr.x), s1 = __half22float2(*(__half2*)&sr.y);
        float2 s2 = __half22float2(*(__half2*)&sr.z), s3 = __half22float2(*(__half2*)&sr.w);
        const float4* bbp = (const float4*)(b2 + l * 8);
        float4 ba = bbp[0], bb = bbp[1];
        float4 o0, o1;
        o0.x = dv * (f0.x + s0.x) + ba.x;
        o0.y = dv * (f0.y + s0.y) + ba.y;
        o0.z = dv * (f1.x + s1.x) + ba.z;
        o0.w = dv * (f1.y + s1.y) + ba.w;
        o1.x = dv * (f2.x + s2.x) + bb.x;
        o1.y = dv * (f2.y + s2.y) + bb.y;
        o1.z = dv * (f3.x + s3.x) + bb.z;
        o1.w = dv * (f3.y + s3.y) + bb.w;
        float4* op = (float4*)(out + (size_t)v * CDIM + l * 8);
        op[0] = o0;
        op[1] = o1;
    }
}

extern "C" void kernel_launch(void* const* d_in, const int* in_sizes, int n_in,
                              void* d_out, int out_size, void* d_ws, size_t ws_size,
                              hipStream_t stream) {
    const float* x  = (const float*)d_in[0];
    const int*   ei = (const int*)d_in[1];
    const float* W1 = (const float*)d_in[2];
    const float* b1 = (const float*)d_in[3];
    const float* W2 = (const float*)d_in[4];
    const float* b2 = (const float*)d_in[5];
    float* out = (float*)d_out;

    int n = in_sizes[0] / F_IN;
    int e = in_sizes[1] / 2;
    const int* srcIdx = ei;
    const int* dstIdx = ei + e;

    int nbk = (n + BK - 1) / BK;  // 391 for n=100K (needs <= 511)
    int nchunks = (e + SC_CHUNK - 1) / SC_CHUNK;

    // workspace layout (4B words):
    //   rc(int2 n) | bucketCursor[512] | col[nbk*BCAP] | dinv[n] |
    //   xs(fp16 [n+1][64]) | h2s(fp16 [n+1][32]) | W1T | W2T | staging[nbk*BCAP]
    int2* rc          = (int2*)d_ws;
    int* bucketCursor = (int*)(rc + n);
    int* col          = bucketCursor + 512;
    float* dinv       = (float*)(col + (size_t)nbk * BCAP);
    _Float16* xs      = (_Float16*)(dinv + n);                     // [n+1][64]
    __half* h2s       = (__half*)(xs + (size_t)(n + 1) * F_IN);    // [n+1][32]
    _Float16* W1T     = (_Float16*)(h2s + (size_t)(n + 1) * CDIM); // [128][64]
    _Float16* W2T     = W1T + HDIM * F_IN;                         // [32][128]
    unsigned* staging = (unsigned*)(W2T + CDIM * HDIM);            // nbk*BCAP

    const int B = 256;

    hipMemsetAsync(bucketCursor, 0, 512 * sizeof(int), stream);

    // build: scatter (fixed-capacity buckets, + wconv/zero-row aux block) -> finalize
    kb_scatter<<<nchunks + 1, B, 0, stream>>>(srcIdx, dstIdx, e, nbk, nchunks,
                                              bucketCursor, staging, W1, W2, W1T, W2T,
                                              (h4*)xs, (h4*)h2s, n);
    kb_finalize<<<nbk, BK, 0, stream>>>(staging, bucketCursor, rc, dinv, col,
                                        x, (h4*)xs, n);

    // fused layer1 gather + MLP (MFMA, 8 nodes/wave) ; then layer2 gather
    k_fused<<<(n + 4 * NPW - 1) / (4 * NPW), B, 0, stream>>>(xs, rc, col, dinv, W1T, b1,
                                                             W2T, h2s, n);
    k_gather2<<<(n + 15) / 16, B, 0, stream>>>((const _Float16*)h2s, rc, col,
                                               dinv, b2, out, n);
}

// Round 20
// 126.843 us; speedup vs baseline: 1.1503x; 1.1503x over previous
//
#include <hip/hip_runtime.h>
#include <hip/hip_fp16.h>

// GCN 2-layer forward, round 20 == R18 (proven best, 128us).
// R17 (wave-pairing) and R19 (8 nodes/wave) both regressed: k_fused's ~55us is
// the L2 transaction-rate floor for 1.6M random 128B row fetches; the 4-quad
// 16-node/wave barrier-free structure is the local optimum.
//   ax[v]  = dinv[v]*(sum xs[s] + xs[v]),  xs = fp16(dinv.*x)
//   h2s    = fp16(dinv .* (relu(ax@W1+b1) @ W2))   [MFMA]
//   out[v] = dinv[v]*(sum h2s[s] + h2s[v]) + b2

#define F_IN 64
#define HDIM 128
#define CDIM 32
#define BK 256          // nodes per bucket (== kb_finalize blockDim)
#define BCAP 6144       // edge capacity per bucket (mean 4090 @ n=100K,E=1.6M)
#define SC_CHUNK 4096   // edges per kb_scatter workgroup

struct h4 { __half2 a, b; };  // 8-byte packed 4x fp16

typedef _Float16 half8 __attribute__((ext_vector_type(8)));
typedef float f32x4 __attribute__((ext_vector_type(4)));

__device__ __forceinline__ __half2 hshfl_xor(__half2 h, int d) {
    union { __half2 h2; int i; } u;
    u.h2 = h;
    u.i = __shfl_xor(u.i, d);
    return u.h2;
}

// ---------- scatter: LDS hist -> cursor reservation -> packed staging ----------
// extra block (blockIdx == nchunks): weight conversion + zero-row padding
__global__ void kb_scatter(const int* __restrict__ src, const int* __restrict__ dst,
                           int e, int nbk, int nchunks, int* __restrict__ bucketCursor,
                           unsigned* __restrict__ staging,
                           const float* __restrict__ W1, const float* __restrict__ W2,
                           _Float16* __restrict__ W1T, _Float16* __restrict__ W2T,
                           h4* __restrict__ xs, h4* __restrict__ h2s4, int n) {
    int tid = threadIdx.x;
    if (blockIdx.x == nchunks) {  // aux block
        for (int i = tid; i < F_IN * HDIM + HDIM * CDIM; i += blockDim.x) {
            if (i < F_IN * HDIM) {
                int k = i >> 7, c = i & 127;
                W1T[c * F_IN + k] = (_Float16)W1[i];
            } else {
                int j = i - F_IN * HDIM;
                int k = j >> 5, c = j & 31;
                W2T[c * HDIM + k] = (_Float16)W2[j];
            }
        }
        h4 z; z.a = __float2half2_rn(0.f); z.b = z.a;
        if (tid < 16) xs[(size_t)n * 16 + tid] = z;               // zero row xs[n]
        else if (tid < 24) h2s4[(size_t)n * 8 + (tid - 16)] = z;  // zero row h2s[n]
        return;
    }
    __shared__ int lh[512];
    __shared__ int lbase[512];
    __shared__ int dstS[SC_CHUNK];
    int c0 = blockIdx.x * SC_CHUNK;
    int m = min(SC_CHUNK, e - c0);
    for (int i = tid; i < nbk; i += blockDim.x) lh[i] = 0;
    __syncthreads();
    for (int i = tid; i < m; i += blockDim.x) {
        int d = dst[c0 + i];
        dstS[i] = d;
        atomicAdd(&lh[d >> 8], 1);
    }
    __syncthreads();
    for (int i = tid; i < nbk; i += blockDim.x) {
        int c = lh[i];
        lbase[i] = c ? atomicAdd(&bucketCursor[i], c) : 0;
        lh[i] = 0;  // becomes local cursor
    }
    __syncthreads();
    for (int i = tid; i < m; i += blockDim.x) {
        int d = dstS[i];
        int b = d >> 8;
        int r = atomicAdd(&lh[b], 1);
        staging[(size_t)b * BCAP + lbase[b] + r] =
            ((unsigned)(d & (BK - 1)) << 24) | (unsigned)src[c0 + i];
    }
}

// fused single-pass: staging copied to LDS during degree count, in-bucket scan
// -> rc(int2 rowptr,deg)/dinv, counting sort from LDS, bucket-local prescale
__global__ __launch_bounds__(256) void kb_finalize(
    const unsigned* __restrict__ staging, const int* __restrict__ bucketCursor,
    int2* __restrict__ rc, float* __restrict__ dinv,
    int* __restrict__ col, const float* __restrict__ x, h4* __restrict__ xs, int n) {
    __shared__ unsigned eS[BCAP];   // 24KB bucket edge cache
    __shared__ int lc[BK];
    __shared__ int lscan[BK];
    __shared__ float dinvS[BK];
    int b = blockIdx.x;
    int tid = threadIdx.x;
    lc[tid] = 0;
    __syncthreads();
    int beg = b * BCAP;
    int ne = bucketCursor[b];
    for (int i = tid; i < ne; i += blockDim.x) {
        unsigned sd = staging[beg + i];
        eS[i] = sd;
        atomicAdd(&lc[sd >> 24], 1);
    }
    __syncthreads();
    int deg = lc[tid];
    lscan[tid] = deg;
    __syncthreads();
    for (int off = 1; off < BK; off <<= 1) {
        int t = (tid >= off) ? lscan[tid - off] : 0;
        __syncthreads();
        lscan[tid] += t;
        __syncthreads();
    }
    int rp = beg + lscan[tid] - deg;   // bucket-padded CSR offset
    int v = b * BK + tid;
    float dv = rsqrtf((float)(deg + 1));
    if (v < n) {
        rc[v] = make_int2(rp, deg);
        dinv[v] = dv;
    }
    dinvS[tid] = dv;
    lc[tid] = rp;  // becomes cursor
    __syncthreads();
    for (int i = tid; i < ne; i += blockDim.x) {
        unsigned sd = eS[i];
        int pos = atomicAdd(&lc[sd >> 24], 1);
        col[pos] = (int)(sd & 0xFFFFFFu);
    }
    // bucket-local prescale: xs[v] = fp16(dinv[v] * x[v])  (coalesced)
    int v0 = b * BK;
    int rows = min(BK, n - v0);
    for (int t = tid; t < rows * 16; t += blockDim.x) {
        int row = t >> 4, q = t & 15;
        float s = dinvS[row];
        float4 val = ((const float4*)x)[(size_t)(v0 + row) * 16 + q];
        h4 o;
        o.a = __floats2half2_rn(val.x * s, val.y * s);
        o.b = __floats2half2_rn(val.z * s, val.w * s);
        xs[(size_t)(v0 + row) * 16 + q] = o;
    }
}

// ---------- fused gather1 + MFMA MLP (R16 structure) ----------
// block = 256 = 4 waves; wave owns 16 nodes: gathers in 4 QUAD steps
// (4 nodes x 2-deep = 8 row-loads in flight/lane) into a wave-private LDS
// arena; axs (stride 72) consumed to registers before hbuf (stride 136)
// overwrites the arena. No __syncthreads.
__global__ __launch_bounds__(256) void k_fused(
    const _Float16* __restrict__ xs, const int2* __restrict__ rc,
    const int* __restrict__ col,
    const float* __restrict__ dinv, const _Float16* __restrict__ W1T,
    const float* __restrict__ b1, const _Float16* __restrict__ W2T,
    __half* __restrict__ h2s, int n) {
    __shared__ _Float16 smem[4][16 * 136 + 8];  // per-wave arena
    int tid = threadIdx.x;
    int w = tid >> 6, lane = tid & 63;
    int m0 = blockIdx.x * 64 + w * 16;
    if (m0 >= n) return;  // wave-uniform; no barriers in this kernel
    int g = lane >> 3, l = lane & 7;
    int lo = lane & 15, hi = lane >> 4;
    _Float16* sm = smem[w];

    // ---- gather phase: 4 quads ----
    for (int p = 0; p < 4; ++p) {
        int v0 = m0 + 4 * p;
        int2 rc0 = make_int2(0, 0), rc1 = rc0, rc2 = rc0, rc3 = rc0;
        if (v0 < n)     rc0 = rc[v0];
        if (v0 + 1 < n) rc1 = rc[v0 + 1];
        if (v0 + 2 < n) rc2 = rc[v0 + 2];
        if (v0 + 3 < n) rc3 = rc[v0 + 3];
        int beg0 = rc0.x, deg0 = rc0.y;
        int beg1 = rc1.x, deg1 = rc1.y;
        int beg2 = rc2.x, deg2 = rc2.y;
        int beg3 = rc3.x, deg3 = rc3.y;
        int dmax = max(max(deg0, deg1), max(deg2, deg3));

        __half2 z = __float2half2_rn(0.f);
        __half2 a00 = z, a01 = z, a02 = z, a03 = z;
        __half2 a10 = z, a11 = z, a12 = z, a13 = z;
        __half2 a20 = z, a21 = z, a22 = z, a23 = z;
        __half2 a30 = z, a31 = z, a32 = z, a33 = z;

        for (int j = g; j < dmax; j += 16) {
            int jb = j + 8;
            int s00 = (j  < deg0) ? col[beg0 + j]  : n;
            int s01 = (jb < deg0) ? col[beg0 + jb] : n;
            int s10 = (j  < deg1) ? col[beg1 + j]  : n;
            int s11 = (jb < deg1) ? col[beg1 + jb] : n;
            int s20 = (j  < deg2) ? col[beg2 + j]  : n;
            int s21 = (jb < deg2) ? col[beg2 + jb] : n;
            int s30 = (j  < deg3) ? col[beg3 + j]  : n;
            int s31 = (jb < deg3) ? col[beg3 + jb] : n;
            float4 r00 = ((const float4*)(xs + (size_t)s00 * F_IN))[l];
            float4 r01 = ((const float4*)(xs + (size_t)s01 * F_IN))[l];
            float4 r10 = ((const float4*)(xs + (size_t)s10 * F_IN))[l];
            float4 r11 = ((const float4*)(xs + (size_t)s11 * F_IN))[l];
            float4 r20 = ((const float4*)(xs + (size_t)s20 * F_IN))[l];
            float4 r21 = ((const float4*)(xs + (size_t)s21 * F_IN))[l];
            float4 r30 = ((const float4*)(xs + (size_t)s30 * F_IN))[l];
            float4 r31 = ((const float4*)(xs + (size_t)s31 * F_IN))[l];
            a00 = __hadd2(a00, *(__half2*)&r00.x); a01 = __hadd2(a01, *(__half2*)&r00.y);
            a02 = __hadd2(a02, *(__half2*)&r00.z); a03 = __hadd2(a03, *(__half2*)&r00.w);
            a00 = __hadd2(a00, *(__half2*)&r01.x); a01 = __hadd2(a01, *(__half2*)&r01.y);
            a02 = __hadd2(a02, *(__half2*)&r01.z); a03 = __hadd2(a03, *(__half2*)&r01.w);
            a10 = __hadd2(a10, *(__half2*)&r10.x); a11 = __hadd2(a11, *(__half2*)&r10.y);
            a12 = __hadd2(a12, *(__half2*)&r10.z); a13 = __hadd2(a13, *(__half2*)&r10.w);
            a10 = __hadd2(a10, *(__half2*)&r11.x); a11 = __hadd2(a11, *(__half2*)&r11.y);
            a12 = __hadd2(a12, *(__half2*)&r11.z); a13 = __hadd2(a13, *(__half2*)&r11.w);
            a20 = __hadd2(a20, *(__half2*)&r20.x); a21 = __hadd2(a21, *(__half2*)&r20.y);
            a22 = __hadd2(a22, *(__half2*)&r20.z); a23 = __hadd2(a23, *(__half2*)&r20.w);
            a20 = __hadd2(a20, *(__half2*)&r21.x); a21 = __hadd2(a21, *(__half2*)&r21.y);
            a22 = __hadd2(a22, *(__half2*)&r21.z); a23 = __hadd2(a23, *(__half2*)&r21.w);
            a30 = __hadd2(a30, *(__half2*)&r30.x); a31 = __hadd2(a31, *(__half2*)&r30.y);
            a32 = __hadd2(a32, *(__half2*)&r30.z); a33 = __hadd2(a33, *(__half2*)&r30.w);
            a30 = __hadd2(a30, *(__half2*)&r31.x); a31 = __hadd2(a31, *(__half2*)&r31.y);
            a32 = __hadd2(a32, *(__half2*)&r31.z); a33 = __hadd2(a33, *(__half2*)&r31.w);
        }

        // packed butterfly across the 8 groups (xor 8, 16, 32)
#pragma unroll
        for (int d = 8; d <= 32; d <<= 1) {
            a00 = __hadd2(a00, hshfl_xor(a00, d)); a01 = __hadd2(a01, hshfl_xor(a01, d));
            a02 = __hadd2(a02, hshfl_xor(a02, d)); a03 = __hadd2(a03, hshfl_xor(a03, d));
            a10 = __hadd2(a10, hshfl_xor(a10, d)); a11 = __hadd2(a11, hshfl_xor(a11, d));
            a12 = __hadd2(a12, hshfl_xor(a12, d)); a13 = __hadd2(a13, hshfl_xor(a13, d));
            a20 = __hadd2(a20, hshfl_xor(a20, d)); a21 = __hadd2(a21, hshfl_xor(a21, d));
            a22 = __hadd2(a22, hshfl_xor(a22, d)); a23 = __hadd2(a23, hshfl_xor(a23, d));
            a30 = __hadd2(a30, hshfl_xor(a30, d)); a31 = __hadd2(a31, hshfl_xor(a31, d));
            a32 = __hadd2(a32, hshfl_xor(a32, d)); a33 = __hadd2(a33, hshfl_xor(a33, d));
        }

        // selection (register moves only) + shared epilogue
        if (g < 4) {
            int v = v0 + g;
            if (v < n) {
                __half2 A0, A1, A2, A3;
                if (g == 0)      { A0 = a00; A1 = a01; A2 = a02; A3 = a03; }
                else if (g == 1) { A0 = a10; A1 = a11; A2 = a12; A3 = a13; }
                else if (g == 2) { A0 = a20; A1 = a21; A2 = a22; A3 = a23; }
                else             { A0 = a30; A1 = a31; A2 = a32; A3 = a33; }
                float dv = dinv[v];
                float4 sr = ((const float4*)(xs + (size_t)v * F_IN))[l];
                float2 f0 = __half22float2(A0), f1 = __half22float2(A1);
                float2 f2 = __half22float2(A2), f3 = __half22float2(A3);
                float2 s0 = __half22float2(*(__half2*)&sr.x);
                float2 s1 = __half22float2(*(__half2*)&sr.y);
                float2 s2 = __half22float2(*(__half2*)&sr.z);
                float2 s3 = __half22float2(*(__half2*)&sr.w);
                __half2 o0 = __floats2half2_rn(dv * (f0.x + s0.x), dv * (f0.y + s0.y));
                __half2 o1 = __floats2half2_rn(dv * (f1.x + s1.x), dv * (f1.y + s1.y));
                __half2 o2 = __floats2half2_rn(dv * (f2.x + s2.x), dv * (f2.y + s2.y));
                __half2 o3 = __floats2half2_rn(dv * (f3.x + s3.x), dv * (f3.y + s3.y));
                float4 o;
                o.x = *(float*)&o0; o.y = *(float*)&o1; o.z = *(float*)&o2; o.w = *(float*)&o3;
                *(float4*)&sm[(4 * p + g) * 72 + l * 8] = o;   // axs row
            }
        }
    }

    // ---- layer 1 MFMA: A from axs (arena, stride 72) ----
    half8 a0 = *(half8*)&sm[lo * 72 + hi * 8];
    half8 a1 = *(half8*)&sm[lo * 72 + 32 + hi * 8];

    float b1v[8];
    f32x4 acc[8];
#pragma unroll
    for (int j = 0; j < 8; ++j) {
        b1v[j] = b1[j * 16 + lo];
        const half8* bptr = (const half8*)(W1T + (size_t)(j * 16 + lo) * F_IN);
        half8 bf0 = bptr[hi];
        half8 bf1 = bptr[4 + hi];
        f32x4 c = {0.f, 0.f, 0.f, 0.f};
        c = __builtin_amdgcn_mfma_f32_16x16x32_f16(a0, bf0, c, 0, 0, 0);
        c = __builtin_amdgcn_mfma_f32_16x16x32_f16(a1, bf1, c, 0, 0, 0);
        acc[j] = c;
    }

    // epilogue 1: bias + relu -> hbuf (arena, stride 136)
#pragma unroll
    for (int j = 0; j < 8; ++j) {
#pragma unroll
        for (int r = 0; r < 4; ++r) {
            float hv = acc[j][r] + b1v[j];
            sm[(hi * 4 + r) * 136 + j * 16 + lo] = (_Float16)(hv > 0.f ? hv : 0.f);
        }
    }

    // ---- layer 2 MFMA: A from hbuf ----
    f32x4 acc2[2] = {{0.f, 0.f, 0.f, 0.f}, {0.f, 0.f, 0.f, 0.f}};
#pragma unroll
    for (int ks = 0; ks < 4; ++ks) {
        half8 a = *(half8*)&sm[lo * 136 + ks * 32 + hi * 8];
#pragma unroll
        for (int t = 0; t < 2; ++t) {
            const half8* b2p = (const half8*)(W2T + (size_t)(t * 16 + lo) * HDIM);
            acc2[t] = __builtin_amdgcn_mfma_f32_16x16x32_f16(a, b2p[ks * 4 + hi], acc2[t], 0, 0, 0);
        }
    }

#pragma unroll
    for (int r = 0; r < 4; ++r) {
        int R = m0 + hi * 4 + r;
        if (R < n) {
            float dv = dinv[R];
            h2s[(size_t)R * CDIM + lo]      = __float2half(dv * acc2[0][r]);
            h2s[(size_t)R * CDIM + 16 + lo] = __float2half(dv * acc2[1][r]);
        }
    }
}

// ---------- gather 2: wave = 4 nodes (16-lane slots), 4-lane groups, 4-deep ----
__global__ void k_gather2(const _Float16* __restrict__ h2s, const int2* __restrict__ rc,
                          const int* __restrict__ col,
                          const float* __restrict__ dinv, const float* __restrict__ b2,
                          float* __restrict__ out, int n) {
    int tid = threadIdx.x;
    int w = tid >> 6, lane = tid & 63;
    int v0w = blockIdx.x * 16 + w * 4;   // first node of this wave
    if (v0w >= n) return;                // wave-uniform
    int slot = lane >> 4;
    int v = v0w + slot;
    bool valid = v < n;
    int g = (lane >> 2) & 3, l = lane & 3;
    int2 rcv = valid ? rc[v] : make_int2(0, 0);
    int beg = rcv.x, deg = rcv.y;

    __half2 zz = __float2half2_rn(0.f);
    __half2 a0 = zz, a1 = zz, a2 = zz, a3 = zz;
    __half2 c0 = zz, c1 = zz, c2 = zz, c3 = zz;
    __half2 d0 = zz, d1 = zz, d2 = zz, d3 = zz;
    __half2 e0 = zz, e1 = zz, e2 = zz, e3 = zz;
    for (int j = g; j < deg; j += 16) {
        int s0 = col[beg + j];
        int s1 = (j + 4  < deg) ? col[beg + j + 4]  : n;
        int s2 = (j + 8  < deg) ? col[beg + j + 8]  : n;
        int s3 = (j + 12 < deg) ? col[beg + j + 12] : n;
        float4 r0 = ((const float4*)(h2s + (size_t)s0 * CDIM))[l];
        float4 r1 = ((const float4*)(h2s + (size_t)s1 * CDIM))[l];
        float4 r2 = ((const float4*)(h2s + (size_t)s2 * CDIM))[l];
        float4 r3 = ((const float4*)(h2s + (size_t)s3 * CDIM))[l];
        a0 = __hadd2(a0, *(__half2*)&r0.x); a1 = __hadd2(a1, *(__half2*)&r0.y);
        a2 = __hadd2(a2, *(__half2*)&r0.z); a3 = __hadd2(a3, *(__half2*)&r0.w);
        c0 = __hadd2(c0, *(__half2*)&r1.x); c1 = __hadd2(c1, *(__half2*)&r1.y);
        c2 = __hadd2(c2, *(__half2*)&r1.z); c3 = __hadd2(c3, *(__half2*)&r1.w);
        d0 = __hadd2(d0, *(__half2*)&r2.x); d1 = __hadd2(d1, *(__half2*)&r2.y);
        d2 = __hadd2(d2, *(__half2*)&r2.z); d3 = __hadd2(d3, *(__half2*)&r2.w);
        e0 = __hadd2(e0, *(__half2*)&r3.x); e1 = __hadd2(e1, *(__half2*)&r3.y);
        e2 = __hadd2(e2, *(__half2*)&r3.z); e3 = __hadd2(e3, *(__half2*)&r3.w);
    }
    a0 = __hadd2(__hadd2(a0, c0), __hadd2(d0, e0));
    a1 = __hadd2(__hadd2(a1, c1), __hadd2(d1, e1));
    a2 = __hadd2(__hadd2(a2, c2), __hadd2(d2, e2));
    a3 = __hadd2(__hadd2(a3, c3), __hadd2(d3, e3));

    // packed butterfly across the 4 groups within the slot (xor 4, 8)
#pragma unroll
    for (int d = 4; d <= 8; d <<= 1) {
        a0 = __hadd2(a0, hshfl_xor(a0, d)); a1 = __hadd2(a1, hshfl_xor(a1, d));
        a2 = __hadd2(a2, hshfl_xor(a2, d)); a3 = __hadd2(a3, hshfl_xor(a3, d));
    }

    if (g == 0 && valid) {
        float dv = dinv[v];
        float4 sr = ((const float4*)(h2s + (size_t)v * CDIM))[l];
        float2 f0 = __half22float2(a0), f1 = __half22float2(a1);
        float2 f2 = __half22float2(a2), f3 = __half22float2(a3);
        float2 s0 = __half22float2(*(__half2*)&sr.x), s1 = __half22float2(*(__half2*)&sr.y);
        float2 s2 = __half22float2(*(__half2*)&sr.z), s3 = __half22float2(*(__half2*)&sr.w);
        const float4* bbp = (const float4*)(b2 + l * 8);
        float4 ba = bbp[0], bb = bbp[1];
        float4 o0, o1;
        o0.x = dv * (f0.x + s0.x) + ba.x;
        o0.y = dv * (f0.y + s0.y) + ba.y;
        o0.z = dv * (f1.x + s1.x) + ba.z;
        o0.w = dv * (f1.y + s1.y) + ba.w;
        o1.x = dv * (f2.x + s2.x) + bb.x;
        o1.y = dv * (f2.y + s2.y) + bb.y;
        o1.z = dv * (f3.x + s3.x) + bb.z;
        o1.w = dv * (f3.y + s3.y) + bb.w;
        float4* op = (float4*)(out + (size_t)v * CDIM + l * 8);
        op[0] = o0;
        op[1] = o1;
    }
}

extern "C" void kernel_launch(void* const* d_in, const int* in_sizes, int n_in,
                              void* d_out, int out_size, void* d_ws, size_t ws_size,
                              hipStream_t stream) {
    const float* x  = (const float*)d_in[0];
    const int*   ei = (const int*)d_in[1];
    const float* W1 = (const float*)d_in[2];
    const float* b1 = (const float*)d_in[3];
    const float* W2 = (const float*)d_in[4];
    const float* b2 = (const float*)d_in[5];
    float* out = (float*)d_out;

    int n = in_sizes[0] / F_IN;
    int e = in_sizes[1] / 2;
    const int* srcIdx = ei;
    const int* dstIdx = ei + e;

    int nbk = (n + BK - 1) / BK;  // 391 for n=100K (needs <= 511)
    int nchunks = (e + SC_CHUNK - 1) / SC_CHUNK;

    // workspace layout (4B words):
    //   rc(int2 n) | bucketCursor[512] | col[nbk*BCAP] | dinv[n] |
    //   xs(fp16 [n+1][64]) | h2s(fp16 [n+1][32]) | W1T | W2T | staging[nbk*BCAP]
    int2* rc          = (int2*)d_ws;
    int* bucketCursor = (int*)(rc + n);
    int* col          = bucketCursor + 512;
    float* dinv       = (float*)(col + (size_t)nbk * BCAP);
    _Float16* xs      = (_Float16*)(dinv + n);                     // [n+1][64]
    __half* h2s       = (__half*)(xs + (size_t)(n + 1) * F_IN);    // [n+1][32]
    _Float16* W1T     = (_Float16*)(h2s + (size_t)(n + 1) * CDIM); // [128][64]
    _Float16* W2T     = W1T + HDIM * F_IN;                         // [32][128]
    unsigned* staging = (unsigned*)(W2T + CDIM * HDIM);            // nbk*BCAP

    const int B = 256;

    hipMemsetAsync(bucketCursor, 0, 512 * sizeof(int), stream);

    // build: scatter (fixed-capacity buckets, + wconv/zero-row aux block) -> finalize
    kb_scatter<<<nchunks + 1, B, 0, stream>>>(srcIdx, dstIdx, e, nbk, nchunks,
                                              bucketCursor, staging, W1, W2, W1T, W2T,
                                              (h4*)xs, (h4*)h2s, n);
    kb_finalize<<<nbk, BK, 0, stream>>>(staging, bucketCursor, rc, dinv, col,
                                        x, (h4*)xs, n);

    // fused layer1 gather + MLP (MFMA) ; then layer2 gather
    k_fused<<<(n + 63) / 64, B, 0, stream>>>(xs, rc, col, dinv, W1T, b1, W2T, h2s, n);
    k_gather2<<<(n + 15) / 16, B, 0, stream>>>((const _Float16*)h2s, rc, col,
                                               dinv, b2, out, n);
}